// Round 10
// baseline (255.582 us; speedup 1.0000x reference)
//
#include <hip/hip_runtime.h>
#include <cstddef>
#include <cstdint>

#define B_   2
#define S_   2048
#define HID  1024
#define NH_  16
#define NKV_ 4
#define DH_  64
#define ROWS (B_ * S_)   // 4096
#define NQKV 1536        // 1024 Q + 256 K + 256 V
#define QSCALE 0.18033688011112042f   // 0.125 * log2(e)  (exp2-domain softmax)

typedef __bf16 bf16_t;
typedef _Float16 f16_t;
typedef bf16_t bf16x8 __attribute__((ext_vector_type(8)));
typedef bf16_t bf16x4 __attribute__((ext_vector_type(4)));
typedef f16_t  f16x8  __attribute__((ext_vector_type(8)));
typedef f16_t  f16x4  __attribute__((ext_vector_type(4)));
typedef float  f32x4  __attribute__((ext_vector_type(4)));

typedef __attribute__((address_space(1))) const uint32_t gu32_t;
typedef __attribute__((address_space(3))) uint32_t lu32_t;

__device__ __forceinline__ void gl_lds16(const void* g, void* l) {
  __builtin_amdgcn_global_load_lds((gu32_t*)g, (lu32_t*)l, 16, 0, 0);
}

// ---------------------------------------------------------------------------
// prep_all: fused cast(hs->bf16) + weight transpose + bias concat + RoPE LUT.
// ---------------------------------------------------------------------------
__global__ void prep_all(const float* __restrict__ hs,
                         const float* __restrict__ Wq, const float* __restrict__ Wk,
                         const float* __restrict__ Wv, const float* __restrict__ Wo,
                         const float* __restrict__ bq, const float* __restrict__ bk,
                         const float* __restrict__ bv,
                         bf16_t* __restrict__ hsb,
                         bf16_t* __restrict__ Wt, bf16_t* __restrict__ Wot,
                         float* __restrict__ ball, float2* __restrict__ lut)
{
  const int bid = blockIdx.x;
  if (bid < 2048) {                        // ---- cast hs -> bf16 ----
    const int i = (bid * 256 + threadIdx.x) * 8;
    float4 a = *(const float4*)(hs + i);
    float4 b = *(const float4*)(hs + i + 4);
    bf16x8 o;
    o[0]=(bf16_t)a.x; o[1]=(bf16_t)a.y; o[2]=(bf16_t)a.z; o[3]=(bf16_t)a.w;
    o[4]=(bf16_t)b.x; o[5]=(bf16_t)b.y; o[6]=(bf16_t)b.z; o[7]=(bf16_t)b.w;
    *(bf16x8*)(hsb + i) = o;
    return;
  }
  if (bid >= 4614) {                       // ---- RoPE LUT ----
    const int idx = (bid - 4614) * 256 + threadIdx.x;   // [0,65536)
    const int s = idx >> 5, j = idx & 31;
    const float L = 0.51905126482615037f;  // log2(1e5)/32
    const float ang = (float)s * exp2f(-L * (float)j);
    lut[idx] = make_float2(cosf(ang), sinf(ang));
    return;
  }
  if (bid >= 4608) {                       // ---- biases ----
    int i = (bid - 4608) * 256 + threadIdx.x;
    if (i < NQKV) ball[i] = (i < 1024) ? bq[i] : ((i < 1280) ? bk[i-1024] : bv[i-1280]);
    return;
  }
  const int wb = bid - 2048;               // ---- weight transpose ----
  const float* src; bf16_t* dst; int N, n0, k0;
  if (wb < 1024)      { src = Wq; dst = Wt;            N = 1024; int t = wb;      n0=(t&31)*32; k0=(t>>5)*32; }
  else if (wb < 1280) { src = Wk; dst = Wt + 1024*HID; N = 256;  int t = wb-1024; n0=(t&7)*32;  k0=(t>>3)*32; }
  else if (wb < 1536) { src = Wv; dst = Wt + 1280*HID; N = 256;  int t = wb-1280; n0=(t&7)*32;  k0=(t>>3)*32; }
  else                { src = Wo; dst = Wot;           N = 1024; int t = wb-1536; n0=(t&31)*32; k0=(t>>5)*32; }
  __shared__ bf16_t T[32][33];
  const int tx = threadIdx.x & 31, ty = threadIdx.x >> 5;
#pragma unroll
  for (int i = 0; i < 4; ++i)
    T[ty + i*8][tx] = (bf16_t)src[(size_t)(k0 + ty + i*8) * N + n0 + tx];
  __syncthreads();
#pragma unroll
  for (int i = 0; i < 4; ++i)
    dst[(size_t)(n0 + ty + i*8) * HID + k0 + tx] = T[tx][ty + i*8];
}

// ---------------------------------------------------------------------------
// bf16 MFMA GEMM, 128(M)x64(N) tile, BK=64, bf16 output (QKV projection).
// ---------------------------------------------------------------------------
__global__ __launch_bounds__(256, 3) void gemm64_b16o(
    const bf16_t* __restrict__ A, const bf16_t* __restrict__ Bt,
    const float* __restrict__ bias, bf16_t* __restrict__ C, int N)
{
  __shared__ bf16_t As[128 * 64];
  __shared__ bf16_t Bs[64 * 64];
  const int tid  = threadIdx.x;
  const int w    = tid >> 6;
  const int lane = tid & 63;
  const int m    = lane & 15;
  const int quad = lane >> 4;
  const int wm   = w >> 1, wn = w & 1;
  const size_t bm = (size_t)blockIdx.y * 128;
  const size_t bn = (size_t)blockIdx.x * 64;

  const int srow = w * 8 + (lane >> 3);
  const int scol = (lane & 7) * 8;
  const bf16_t* Ag = A  + (bm + srow) * HID + scol;
  const bf16_t* Bg = Bt + (bn + srow) * HID + scol;

  f32x4 acc[4][2];
#pragma unroll
  for (int i = 0; i < 4; ++i)
#pragma unroll
    for (int j = 0; j < 2; ++j) acc[i][j] = (f32x4){0.f, 0.f, 0.f, 0.f};

  for (int k0 = 0; k0 < HID; k0 += 64) {
    __syncthreads();
#pragma unroll
    for (int i = 0; i < 4; ++i)
      gl_lds16(Ag + (size_t)(i * 32) * HID + k0, &As[(w * 8 + i * 32) * 64]);
#pragma unroll
    for (int i = 0; i < 2; ++i)
      gl_lds16(Bg + (size_t)(i * 32) * HID + k0, &Bs[(w * 8 + i * 32) * 64]);
    __syncthreads();
#pragma unroll
    for (int ks = 0; ks < 2; ++ks) {
      bf16x8 af[4], bfr[2];
#pragma unroll
      for (int mt = 0; mt < 4; ++mt)
        af[mt] = *(const bf16x8*)&As[(wm * 64 + mt * 16 + m) * 64 + ks * 32 + quad * 8];
#pragma unroll
      for (int nt = 0; nt < 2; ++nt)
        bfr[nt] = *(const bf16x8*)&Bs[(wn * 32 + nt * 16 + m) * 64 + ks * 32 + quad * 8];
#pragma unroll
      for (int mt = 0; mt < 4; ++mt)
#pragma unroll
        for (int nt = 0; nt < 2; ++nt)
          acc[mt][nt] = __builtin_amdgcn_mfma_f32_16x16x32_bf16(bfr[nt], af[mt], acc[mt][nt], 0, 0, 0);
    }
  }
#pragma unroll
  for (int mt = 0; mt < 4; ++mt) {
    const size_t row = bm + wm * 64 + mt * 16 + m;
#pragma unroll
    for (int nt = 0; nt < 2; ++nt) {
      const size_t col = bn + wn * 32 + nt * 16 + quad * 4;
      float4 bb = *(const float4*)&bias[col];
      bf16x4 o;
      o[0] = (bf16_t)(acc[mt][nt][0] + bb.x);
      o[1] = (bf16_t)(acc[mt][nt][1] + bb.y);
      o[2] = (bf16_t)(acc[mt][nt][2] + bb.z);
      o[3] = (bf16_t)(acc[mt][nt][3] + bb.w);
      *(bf16x4*)&C[row * N + col] = o;
    }
  }
}

// ---------------------------------------------------------------------------
// same structure, fp32 output (O-projection).
// ---------------------------------------------------------------------------
__global__ __launch_bounds__(256, 3) void gemm64_f32o(
    const bf16_t* __restrict__ A, const bf16_t* __restrict__ Bt,
    const float* __restrict__ bias, float* __restrict__ C, int N)
{
  __shared__ bf16_t As[128 * 64];
  __shared__ bf16_t Bs[64 * 64];
  const int tid  = threadIdx.x;
  const int w    = tid >> 6;
  const int lane = tid & 63;
  const int m    = lane & 15;
  const int quad = lane >> 4;
  const int wm   = w >> 1, wn = w & 1;
  const size_t bm = (size_t)blockIdx.y * 128;
  const size_t bn = (size_t)blockIdx.x * 64;

  const int srow = w * 8 + (lane >> 3);
  const int scol = (lane & 7) * 8;
  const bf16_t* Ag = A  + (bm + srow) * HID + scol;
  const bf16_t* Bg = Bt + (bn + srow) * HID + scol;

  f32x4 acc[4][2];
#pragma unroll
  for (int i = 0; i < 4; ++i)
#pragma unroll
    for (int j = 0; j < 2; ++j) acc[i][j] = (f32x4){0.f, 0.f, 0.f, 0.f};

  for (int k0 = 0; k0 < HID; k0 += 64) {
    __syncthreads();
#pragma unroll
    for (int i = 0; i < 4; ++i)
      gl_lds16(Ag + (size_t)(i * 32) * HID + k0, &As[(w * 8 + i * 32) * 64]);
#pragma unroll
    for (int i = 0; i < 2; ++i)
      gl_lds16(Bg + (size_t)(i * 32) * HID + k0, &Bs[(w * 8 + i * 32) * 64]);
    __syncthreads();
#pragma unroll
    for (int ks = 0; ks < 2; ++ks) {
      bf16x8 af[4], bfr[2];
#pragma unroll
      for (int mt = 0; mt < 4; ++mt)
        af[mt] = *(const bf16x8*)&As[(wm * 64 + mt * 16 + m) * 64 + ks * 32 + quad * 8];
#pragma unroll
      for (int nt = 0; nt < 2; ++nt)
        bfr[nt] = *(const bf16x8*)&Bs[(wn * 32 + nt * 16 + m) * 64 + ks * 32 + quad * 8];
#pragma unroll
      for (int mt = 0; mt < 4; ++mt)
#pragma unroll
        for (int nt = 0; nt < 2; ++nt)
          acc[mt][nt] = __builtin_amdgcn_mfma_f32_16x16x32_bf16(bfr[nt], af[mt], acc[mt][nt], 0, 0, 0);
    }
  }
#pragma unroll
  for (int mt = 0; mt < 4; ++mt) {
    const size_t row = bm + wm * 64 + mt * 16 + m;
#pragma unroll
    for (int nt = 0; nt < 2; ++nt) {
      const size_t col = bn + wn * 32 + nt * 16 + quad * 4;
      float4 bb = *(const float4*)&bias[col];
      float4 o;
      o.x = acc[mt][nt][0] + bb.x; o.y = acc[mt][nt][1] + bb.y;
      o.z = acc[mt][nt][2] + bb.z; o.w = acc[mt][nt][3] + bb.w;
      *(float4*)&C[row * N + col] = o;
    }
  }
}

// ---------------------------------------------------------------------------
// prep_kv: K -> plain roped rows [key][d] (bf16, fragment-readable directly).
//          V -> f16 frag-ordered image: idx = (d*4 + quad)*16 + cb*4 + j,
//               where key = cb*16 + quad*4 + j.  8 KB per (b,kvh,kt) each.
// ---------------------------------------------------------------------------
__global__ void prep_kv(const bf16_t* __restrict__ QKVb, const float2* __restrict__ lut,
                        bf16_t* __restrict__ Kimg, f16_t* __restrict__ Vimg)
{
  __shared__ bf16_t Lv[64][72];
  const int bid = blockIdx.x, t = threadIdx.x;
  const int kt = bid & 31, kvh = (bid >> 5) & 3, b = bid >> 7;
  const size_t img = ((size_t)(b * NKV_ + kvh) * 32 + kt) * 4096;

  {   // stage V (coalesced) for transpose
    const int r0 = t >> 3, c8 = (t & 7) * 8;
#pragma unroll
    for (int i = 0; i < 2; ++i) {
      const int r = r0 + i * 32;
      const bf16_t* src = QKVb + (size_t)(b * S_ + kt * 64 + r) * NQKV + 1280 + kvh * DH_ + c8;
      *(bf16x8*)&Lv[r][c8] = *(const bf16x8*)src;
    }
  }
  {   // K: rope + plain row write (coalesced-ish, 16B stores)
    const int key = t & 63, cg = t >> 6;        // d0 = cg*16
    const int srow = kt * 64 + key;
    const bf16_t* p = QKVb + (size_t)(b * S_ + srow) * NQKV + 1024 + kvh * DH_ + cg * 16;
    bf16x8 a = *(const bf16x8*)p;
    bf16x8 c = *(const bf16x8*)(p + 8);
    const float2* lp = lut + srow * 32 + ((cg & 1) * 16);
    float v[16];
#pragma unroll
    for (int i = 0; i < 8; ++i) { v[i] = (float)a[i]; v[i + 8] = (float)c[i]; }
    bf16x8 o0, o1;
#pragma unroll
    for (int j = 0; j < 8; ++j) {
      const float2 ce = lp[2 * j], co = lp[2 * j + 1];
      const float y0 = v[2*j] * ce.x - v[2*j+1] * ce.y;
      const float y1 = v[2*j+1] * co.x + v[2*j] * co.y;
      if (j < 4) { o0[2*j] = (bf16_t)y0; o0[2*j+1] = (bf16_t)y1; }
      else       { o1[2*(j-4)] = (bf16_t)y0; o1[2*(j-4)+1] = (bf16_t)y1; }
    }
    *(bf16x8*)&Kimg[img + key * 64 + cg * 16]     = o0;
    *(bf16x8*)&Kimg[img + key * 64 + cg * 16 + 8] = o1;
  }
  __syncthreads();
  {   // V: transpose into frag-ordered image
    const int d = t & 63, cg = t >> 6;          // key groups g = cg*4 .. +3
#pragma unroll
    for (int g4 = 0; g4 < 4; ++g4) {
      const int g = cg * 4 + g4;                // g = cb*4 + quad
      f16x4 o;
#pragma unroll
      for (int j = 0; j < 4; ++j)
        o[j] = (f16_t)(float)Lv[g * 4 + j][d];
      *(f16x4*)&Vimg[img + (d * 4 + (g & 3)) * 16 + (g >> 2) * 4] = o;
    }
  }
}

// ---------------------------------------------------------------------------
// attn_v7: ONE WAVE PER BLOCK, NO LDS. K/V fragments loaded straight from
// frag-ordered global images into VGPRs, register double-buffered across
// k-tiles (unroll-2). Compiler emits fine-grained per-register vmcnt waits.
// Static softmax (exp2 domain, Q pre-scaled by 0.125*log2e).
// ---------------------------------------------------------------------------
struct KVFrag {
  bf16x8 k[4][2];   // [cb][kc]
  f16x4  v[4][4];   // [dblk][cb]
};

__device__ __forceinline__ void load_frags(const bf16_t* __restrict__ Kg,
                                           const f16_t* __restrict__ Vg,
                                           int kt, int m, int quad, KVFrag& f)
{
  const bf16_t* kp = Kg + (size_t)kt * 4096 + m * 64 + quad * 8;
#pragma unroll
  for (int cb = 0; cb < 4; ++cb)
#pragma unroll
    for (int kc = 0; kc < 2; ++kc)
      f.k[cb][kc] = *(const bf16x8*)(kp + cb * 1024 + kc * 32);
  const f16_t* vp = Vg + (size_t)kt * 4096 + (m * 4 + quad) * 16;
#pragma unroll
  for (int dblk = 0; dblk < 4; ++dblk)
#pragma unroll
    for (int c2 = 0; c2 < 2; ++c2) {
      f16x8 t = *(const f16x8*)(vp + dblk * 1024 + c2 * 8);
      f.v[dblk][c2*2]   = __builtin_shufflevector(t, t, 0, 1, 2, 3);
      f.v[dblk][c2*2+1] = __builtin_shufflevector(t, t, 4, 5, 6, 7);
    }
}

__device__ __forceinline__ void tile_compute(const KVFrag& f, int mreg, int kbase,
    int q0w, int m, int quad, const bf16x8 (&aq)[2][2],
    f32x4 (&oacc)[2][4], float (&lpart)[2])
{
  const uint64_t mb = __ballot(mreg != 0);
  // ---- S^T = K . Q^T ----
  f32x4 sc[2][4];
#pragma unroll
  for (int mt = 0; mt < 2; ++mt)
#pragma unroll
    for (int cb = 0; cb < 4; ++cb) sc[mt][cb] = (f32x4){0.f,0.f,0.f,0.f};
#pragma unroll
  for (int cb = 0; cb < 4; ++cb)
#pragma unroll
    for (int mt = 0; mt < 2; ++mt) {
      sc[mt][cb] = __builtin_amdgcn_mfma_f32_16x16x32_bf16(f.k[cb][0], aq[mt][0], sc[mt][cb], 0, 0, 0);
      sc[mt][cb] = __builtin_amdgcn_mfma_f32_16x16x32_bf16(f.k[cb][1], aq[mt][1], sc[mt][cb], 0, 0, 0);
    }
  // ---- static softmax ----
  f16x4 bp[2][4];
#pragma unroll
  for (int mt = 0; mt < 2; ++mt) {
    const bool needm = (kbase + 63 > q0w + mt*16) || (mb != ~0ull);
    if (needm) {
      const int qv = q0w + mt*16 + m;
#pragma unroll
      for (int cb = 0; cb < 4; ++cb)
#pragma unroll
        for (int r = 0; r < 4; ++r) {
          const int idx = cb*16 + quad*4 + r;
          const bool ok = (kbase + idx <= qv) && ((mb >> idx) & 1);
          sc[mt][cb][r] = ok ? sc[mt][cb][r] : -1e38f;
        }
    }
    float sum = 0.f;
#pragma unroll
    for (int cb = 0; cb < 4; ++cb) {
      f16x4 pp;
#pragma unroll
      for (int r = 0; r < 4; ++r) {
        const float p = exp2f(sc[mt][cb][r]);
        sum += p;
        pp[r] = (f16_t)p;
      }
      bp[mt][cb] = pp;
    }
    lpart[mt] += sum;
  }
  // ---- O^T += V^T . P^T ----
#pragma unroll
  for (int cb = 0; cb < 4; ++cb)
#pragma unroll
    for (int mt = 0; mt < 2; ++mt)
#pragma unroll
      for (int dblk = 0; dblk < 4; ++dblk)
        oacc[mt][dblk] = __builtin_amdgcn_mfma_f32_16x16x16f16(f.v[dblk][cb], bp[mt][cb], oacc[mt][dblk], 0, 0, 0);
}

__global__ __launch_bounds__(64) void attn_v7(
    const bf16_t* __restrict__ QKVb, const float2* __restrict__ lut,
    const bf16_t* __restrict__ Kt2, const f16_t* __restrict__ Vt2,
    const int* __restrict__ amask, bf16_t* __restrict__ Ab)
{
  const int lane = threadIdx.x;
  const int m    = lane & 15;
  const int quad = lane >> 4;
  const int h    = blockIdx.y;
  const int b    = blockIdx.z;
  const int kvh  = h >> 2;
  const int qt   = 63 - blockIdx.x;        // long blocks first
  const int q0w  = qt * 32;
  const int nkt  = ((q0w + 31) >> 6) + 1;

  // ---- Q fragments with fused RoPE + scale ----
  bf16x8 aq[2][2];
#pragma unroll
  for (int mt = 0; mt < 2; ++mt) {
    const int spos = q0w + mt * 16 + m;
    const bf16_t* qsrc = QKVb + (size_t)(b * S_ + spos) * NQKV + h * DH_;
    float2 l8[8];
#pragma unroll
    for (int j = 0; j < 8; ++j) l8[j] = lut[spos * 32 + quad * 8 + j];
#pragma unroll
    for (int kc = 0; kc < 2; ++kc) {
      bf16x8 x = *(const bf16x8*)(qsrc + kc * 32 + quad * 8);
      bf16x8 y;
#pragma unroll
      for (int i = 0; i < 4; ++i) {
        const float x0 = (float)x[2*i], x1 = (float)x[2*i+1];
        y[2*i]   = (bf16_t)((x0 * l8[2*i].x   - x1 * l8[2*i].y)   * QSCALE);
        y[2*i+1] = (bf16_t)((x1 * l8[2*i+1].x + x0 * l8[2*i+1].y) * QSCALE);
      }
      aq[mt][kc] = y;
    }
  }

  f32x4 oacc[2][4];
#pragma unroll
  for (int mt = 0; mt < 2; ++mt)
#pragma unroll
    for (int d = 0; d < 4; ++d) oacc[mt][d] = (f32x4){0.f,0.f,0.f,0.f};
  float lpart[2] = {0.f, 0.f};

  const size_t imgbase = ((size_t)(b * NKV_ + kvh) * 32) * 4096;
  const bf16_t* Kg = Kt2 + imgbase;
  const f16_t*  Vg = Vt2 + imgbase;
  const int* amp = amask + b * S_;

  // ---- register double-buffered pipeline (unroll-2) ----
  KVFrag fA, fB;
  load_frags(Kg, Vg, 0, m, quad, fA);
  int m0 = amp[lane];
  int m1 = 0;
  for (int kt = 0; kt < nkt; kt += 2) {
    const bool h1 = (kt + 1 < nkt);
    if (h1) { load_frags(Kg, Vg, kt + 1, m, quad, fB); m1 = amp[(kt + 1) * 64 + lane]; }
    tile_compute(fA, m0, kt * 64, q0w, m, quad, aq, oacc, lpart);
    if (!h1) break;
    if (kt + 2 < nkt) { load_frags(Kg, Vg, kt + 2, m, quad, fA); m0 = amp[(kt + 2) * 64 + lane]; }
    tile_compute(fB, m1, (kt + 1) * 64, q0w, m, quad, aq, oacc, lpart);
  }

  // ---- epilogue: reduce l across quads, store O ----
#pragma unroll
  for (int mt = 0; mt < 2; ++mt) {
    float l = lpart[mt];
    l += __shfl_xor(l, 16);
    l += __shfl_xor(l, 32);
    const float inv = 1.0f / l;
    const size_t row = (size_t)(b * S_ + q0w + mt*16 + m);
#pragma unroll
    for (int dblk = 0; dblk < 4; ++dblk) {
      bf16x4 o;
      o[0] = (bf16_t)(oacc[mt][dblk][0] * inv);
      o[1] = (bf16_t)(oacc[mt][dblk][1] * inv);
      o[2] = (bf16_t)(oacc[mt][dblk][2] * inv);
      o[3] = (bf16_t)(oacc[mt][dblk][3] * inv);
      *(bf16x4*)&Ab[row * HID + h * DH_ + dblk * 16 + quad * 4] = o;
    }
  }
}

// ---------------------------------------------------------------------------
extern "C" void kernel_launch(void* const* d_in, const int* in_sizes, int n_in,
                              void* d_out, int out_size, void* d_ws, size_t ws_size,
                              hipStream_t stream)
{
  const float* hs    = (const float*)d_in[0];
  const int*   amask = (const int*)  d_in[1];
  const float* Wq    = (const float*)d_in[2];
  const float* bq    = (const float*)d_in[3];
  const float* Wk    = (const float*)d_in[4];
  const float* bk    = (const float*)d_in[5];
  const float* Wv    = (const float*)d_in[6];
  const float* bv    = (const float*)d_in[7];
  const float* Wo    = (const float*)d_in[8];
  const float* bo    = (const float*)d_in[9];
  float* out = (float*)d_out;

  // workspace layout (~31 MB)
  bf16_t* QKVb = (bf16_t*)d_ws;                            // 12.6 MB (live through attn)
  bf16_t* hsb  = QKVb + (size_t)ROWS * NQKV;               // 8 MB (Ab aliases after QKV GEMM)
  bf16_t* Wt   = hsb + (size_t)ROWS * HID;                 // 3 MB
  bf16_t* Wot  = Wt + (size_t)NQKV * HID;                  // 2 MB
  float*  ball = (float*)(Wot + (size_t)HID * HID);        // 6 KB
  bf16_t* Kimg = (bf16_t*)(ball + NQKV);                   // 2 MB
  f16_t*  Vimg = (f16_t*)(Kimg + (size_t)B_*NKV_*32*4096); // 2 MB
  float2* lut  = (float2*)(Vimg + (size_t)B_*NKV_*32*4096);// 0.5 MB
  bf16_t* Ab   = hsb;                                      // alias (hsb dead after QKV GEMM)

  // fused prep: cast + weight transpose + biases + RoPE LUT
  prep_all<<<4870, 256, 0, stream>>>(hs, Wq, Wk, Wv, Wo, bq, bk, bv,
                                     hsb, Wt, Wot, ball, lut);

  // QKV projection (bf16 out, 768 blocks = 3/CU)
  gemm64_b16o<<<dim3(NQKV/64, ROWS/128), 256, 0, stream>>>(hsb, Wt, ball, QKVb, NQKV);

  // K/V frag-ordered images (roped K rows, transposed V)
  prep_kv<<<256, 256, 0, stream>>>(QKVb, lut, Kimg, Vimg);

  // attention (1 wave/block, no LDS, register-pipelined)
  attn_v7<<<dim3(64, NH_, B_), 64, 0, stream>>>(QKVb, lut, Kimg, Vimg, amask, Ab);

  // output projection (512 blocks = 2/CU)
  gemm64_f32o<<<dim3(HID/64, ROWS/128), 256, 0, stream>>>(Ab, Wot, bo, out, HID);
}

// Round 11
// 207.995 us; speedup vs baseline: 1.2288x; 1.2288x over previous
//
#include <hip/hip_runtime.h>
#include <cstddef>
#include <cstdint>

#define B_   2
#define S_   2048
#define HID  1024
#define NH_  16
#define NKV_ 4
#define DH_  64
#define ROWS (B_ * S_)   // 4096
#define NQKV 1536        // 1024 Q + 256 K + 256 V
#define QSCALE 0.18033688011112042f   // 0.125 * log2(e)  (exp2-domain softmax)

typedef __bf16 bf16_t;
typedef _Float16 f16_t;
typedef bf16_t bf16x8 __attribute__((ext_vector_type(8)));
typedef bf16_t bf16x4 __attribute__((ext_vector_type(4)));
typedef f16_t  f16x8  __attribute__((ext_vector_type(8)));
typedef f16_t  f16x4  __attribute__((ext_vector_type(4)));
typedef float  f32x4  __attribute__((ext_vector_type(4)));

typedef __attribute__((address_space(1))) const uint32_t gu32_t;
typedef __attribute__((address_space(3))) uint32_t lu32_t;

__device__ __forceinline__ void gl_lds16(const void* g, void* l) {
  __builtin_amdgcn_global_load_lds((gu32_t*)g, (lu32_t*)l, 16, 0, 0);
}

// ---------------------------------------------------------------------------
// prep_all: fused cast(hs->bf16) + weight transpose + bias concat + RoPE LUT.
// ---------------------------------------------------------------------------
__global__ void prep_all(const float* __restrict__ hs,
                         const float* __restrict__ Wq, const float* __restrict__ Wk,
                         const float* __restrict__ Wv, const float* __restrict__ Wo,
                         const float* __restrict__ bq, const float* __restrict__ bk,
                         const float* __restrict__ bv,
                         bf16_t* __restrict__ hsb,
                         bf16_t* __restrict__ Wt, bf16_t* __restrict__ Wot,
                         float* __restrict__ ball, float2* __restrict__ lut)
{
  const int bid = blockIdx.x;
  if (bid < 2048) {                        // ---- cast hs -> bf16 ----
    const int i = (bid * 256 + threadIdx.x) * 8;
    float4 a = *(const float4*)(hs + i);
    float4 b = *(const float4*)(hs + i + 4);
    bf16x8 o;
    o[0]=(bf16_t)a.x; o[1]=(bf16_t)a.y; o[2]=(bf16_t)a.z; o[3]=(bf16_t)a.w;
    o[4]=(bf16_t)b.x; o[5]=(bf16_t)b.y; o[6]=(bf16_t)b.z; o[7]=(bf16_t)b.w;
    *(bf16x8*)(hsb + i) = o;
    return;
  }
  if (bid >= 4614) {                       // ---- RoPE LUT ----
    const int idx = (bid - 4614) * 256 + threadIdx.x;   // [0,65536)
    const int s = idx >> 5, j = idx & 31;
    const float L = 0.51905126482615037f;  // log2(1e5)/32
    const float ang = (float)s * exp2f(-L * (float)j);
    lut[idx] = make_float2(cosf(ang), sinf(ang));
    return;
  }
  if (bid >= 4608) {                       // ---- biases ----
    int i = (bid - 4608) * 256 + threadIdx.x;
    if (i < NQKV) ball[i] = (i < 1024) ? bq[i] : ((i < 1280) ? bk[i-1024] : bv[i-1280]);
    return;
  }
  const int wb = bid - 2048;               // ---- weight transpose ----
  const float* src; bf16_t* dst; int N, n0, k0;
  if (wb < 1024)      { src = Wq; dst = Wt;            N = 1024; int t = wb;      n0=(t&31)*32; k0=(t>>5)*32; }
  else if (wb < 1280) { src = Wk; dst = Wt + 1024*HID; N = 256;  int t = wb-1024; n0=(t&7)*32;  k0=(t>>3)*32; }
  else if (wb < 1536) { src = Wv; dst = Wt + 1280*HID; N = 256;  int t = wb-1280; n0=(t&7)*32;  k0=(t>>3)*32; }
  else                { src = Wo; dst = Wot;           N = 1024; int t = wb-1536; n0=(t&31)*32; k0=(t>>5)*32; }
  __shared__ bf16_t T[32][33];
  const int tx = threadIdx.x & 31, ty = threadIdx.x >> 5;
#pragma unroll
  for (int i = 0; i < 4; ++i)
    T[ty + i*8][tx] = (bf16_t)src[(size_t)(k0 + ty + i*8) * N + n0 + tx];
  __syncthreads();
#pragma unroll
  for (int i = 0; i < 4; ++i)
    dst[(size_t)(n0 + ty + i*8) * HID + k0 + tx] = T[tx][ty + i*8];
}

// ---------------------------------------------------------------------------
// bf16 MFMA GEMM, 128(M)x64(N) tile, BK=64, LDS double-buffered (prefetch
// issued AFTER the barrier so the vmcnt drain overlaps compute). bf16 out.
// ---------------------------------------------------------------------------
__global__ __launch_bounds__(256, 3) void gemm64_b16o(
    const bf16_t* __restrict__ A, const bf16_t* __restrict__ Bt,
    const float* __restrict__ bias, bf16_t* __restrict__ C, int N)
{
  __shared__ bf16_t As[2][128 * 64];
  __shared__ bf16_t Bs[2][64 * 64];
  const int tid  = threadIdx.x;
  const int w    = tid >> 6;
  const int lane = tid & 63;
  const int m    = lane & 15;
  const int quad = lane >> 4;
  const int wm   = w >> 1, wn = w & 1;
  const size_t bm = (size_t)blockIdx.y * 128;
  const size_t bn = (size_t)blockIdx.x * 64;

  const int srow = w * 8 + (lane >> 3);
  const int scol = (lane & 7) * 8;
  const bf16_t* Ag = A  + (bm + srow) * HID + scol;
  const bf16_t* Bg = Bt + (bn + srow) * HID + scol;

  f32x4 acc[4][2];
#pragma unroll
  for (int i = 0; i < 4; ++i)
#pragma unroll
    for (int j = 0; j < 2; ++j) acc[i][j] = (f32x4){0.f, 0.f, 0.f, 0.f};

  // prologue stage k0=0 into buf 0
#pragma unroll
  for (int i = 0; i < 4; ++i)
    gl_lds16(Ag + (size_t)(i * 32) * HID, &As[0][(w * 8 + i * 32) * 64]);
#pragma unroll
  for (int i = 0; i < 2; ++i)
    gl_lds16(Bg + (size_t)(i * 32) * HID, &Bs[0][(w * 8 + i * 32) * 64]);

  int p = 0;
  for (int k0 = 0; k0 < HID; k0 += 64) {
    __syncthreads();                       // drains buf[p]'s DMA (issued last iter)
    if (k0 + 64 < HID) {                   // prefetch next into buf[p^1]
#pragma unroll
      for (int i = 0; i < 4; ++i)
        gl_lds16(Ag + (size_t)(i * 32) * HID + k0 + 64, &As[p^1][(w * 8 + i * 32) * 64]);
#pragma unroll
      for (int i = 0; i < 2; ++i)
        gl_lds16(Bg + (size_t)(i * 32) * HID + k0 + 64, &Bs[p^1][(w * 8 + i * 32) * 64]);
    }
#pragma unroll
    for (int ks = 0; ks < 2; ++ks) {
      bf16x8 af[4], bfr[2];
#pragma unroll
      for (int mt = 0; mt < 4; ++mt)
        af[mt] = *(const bf16x8*)&As[p][(wm * 64 + mt * 16 + m) * 64 + ks * 32 + quad * 8];
#pragma unroll
      for (int nt = 0; nt < 2; ++nt)
        bfr[nt] = *(const bf16x8*)&Bs[p][(wn * 32 + nt * 16 + m) * 64 + ks * 32 + quad * 8];
#pragma unroll
      for (int mt = 0; mt < 4; ++mt)
#pragma unroll
        for (int nt = 0; nt < 2; ++nt)
          acc[mt][nt] = __builtin_amdgcn_mfma_f32_16x16x32_bf16(bfr[nt], af[mt], acc[mt][nt], 0, 0, 0);
    }
    p ^= 1;
  }
#pragma unroll
  for (int mt = 0; mt < 4; ++mt) {
    const size_t row = bm + wm * 64 + mt * 16 + m;
#pragma unroll
    for (int nt = 0; nt < 2; ++nt) {
      const size_t col = bn + wn * 32 + nt * 16 + quad * 4;
      float4 bb = *(const float4*)&bias[col];
      bf16x4 o;
      o[0] = (bf16_t)(acc[mt][nt][0] + bb.x);
      o[1] = (bf16_t)(acc[mt][nt][1] + bb.y);
      o[2] = (bf16_t)(acc[mt][nt][2] + bb.z);
      o[3] = (bf16_t)(acc[mt][nt][3] + bb.w);
      *(bf16x4*)&C[row * N + col] = o;
    }
  }
}

// ---------------------------------------------------------------------------
// same structure, fp32 output (O-projection).
// ---------------------------------------------------------------------------
__global__ __launch_bounds__(256, 3) void gemm64_f32o(
    const bf16_t* __restrict__ A, const bf16_t* __restrict__ Bt,
    const float* __restrict__ bias, float* __restrict__ C, int N)
{
  __shared__ bf16_t As[2][128 * 64];
  __shared__ bf16_t Bs[2][64 * 64];
  const int tid  = threadIdx.x;
  const int w    = tid >> 6;
  const int lane = tid & 63;
  const int m    = lane & 15;
  const int quad = lane >> 4;
  const int wm   = w >> 1, wn = w & 1;
  const size_t bm = (size_t)blockIdx.y * 128;
  const size_t bn = (size_t)blockIdx.x * 64;

  const int srow = w * 8 + (lane >> 3);
  const int scol = (lane & 7) * 8;
  const bf16_t* Ag = A  + (bm + srow) * HID + scol;
  const bf16_t* Bg = Bt + (bn + srow) * HID + scol;

  f32x4 acc[4][2];
#pragma unroll
  for (int i = 0; i < 4; ++i)
#pragma unroll
    for (int j = 0; j < 2; ++j) acc[i][j] = (f32x4){0.f, 0.f, 0.f, 0.f};

#pragma unroll
  for (int i = 0; i < 4; ++i)
    gl_lds16(Ag + (size_t)(i * 32) * HID, &As[0][(w * 8 + i * 32) * 64]);
#pragma unroll
  for (int i = 0; i < 2; ++i)
    gl_lds16(Bg + (size_t)(i * 32) * HID, &Bs[0][(w * 8 + i * 32) * 64]);

  int p = 0;
  for (int k0 = 0; k0 < HID; k0 += 64) {
    __syncthreads();
    if (k0 + 64 < HID) {
#pragma unroll
      for (int i = 0; i < 4; ++i)
        gl_lds16(Ag + (size_t)(i * 32) * HID + k0 + 64, &As[p^1][(w * 8 + i * 32) * 64]);
#pragma unroll
      for (int i = 0; i < 2; ++i)
        gl_lds16(Bg + (size_t)(i * 32) * HID + k0 + 64, &Bs[p^1][(w * 8 + i * 32) * 64]);
    }
#pragma unroll
    for (int ks = 0; ks < 2; ++ks) {
      bf16x8 af[4], bfr[2];
#pragma unroll
      for (int mt = 0; mt < 4; ++mt)
        af[mt] = *(const bf16x8*)&As[p][(wm * 64 + mt * 16 + m) * 64 + ks * 32 + quad * 8];
#pragma unroll
      for (int nt = 0; nt < 2; ++nt)
        bfr[nt] = *(const bf16x8*)&Bs[p][(wn * 32 + nt * 16 + m) * 64 + ks * 32 + quad * 8];
#pragma unroll
      for (int mt = 0; mt < 4; ++mt)
#pragma unroll
        for (int nt = 0; nt < 2; ++nt)
          acc[mt][nt] = __builtin_amdgcn_mfma_f32_16x16x32_bf16(bfr[nt], af[mt], acc[mt][nt], 0, 0, 0);
    }
    p ^= 1;
  }
#pragma unroll
  for (int mt = 0; mt < 4; ++mt) {
    const size_t row = bm + wm * 64 + mt * 16 + m;
#pragma unroll
    for (int nt = 0; nt < 2; ++nt) {
      const size_t col = bn + wn * 32 + nt * 16 + quad * 4;
      float4 bb = *(const float4*)&bias[col];
      float4 o;
      o.x = acc[mt][nt][0] + bb.x; o.y = acc[mt][nt][1] + bb.y;
      o.z = acc[mt][nt][2] + bb.z; o.w = acc[mt][nt][3] + bb.w;
      *(float4*)&C[row * N + col] = o;
    }
  }
}

// ---------------------------------------------------------------------------
// prep_kv (R8-proven): LDS-staged K/V tile-image builder, one block per
// (b,kvh,kt).  K image: [key][slot*8+(d&7)], slot=(d>>3)^(key&7)   (bf16)
//              V image: [d][slot*4+(key&3)], slot=(key>>2)^(d&15)  (f16)
// ---------------------------------------------------------------------------
__global__ void prep_kv(const bf16_t* __restrict__ QKVb, const float2* __restrict__ lut,
                        bf16_t* __restrict__ Kimg, f16_t* __restrict__ Vimg)
{
  __shared__ bf16_t Lk[64][72];
  __shared__ bf16_t Lv[64][72];
  const int bid = blockIdx.x, t = threadIdx.x;
  const int kt = bid & 31, kvh = (bid >> 5) & 3, b = bid >> 7;
  const size_t img = ((size_t)(b * NKV_ + kvh) * 32 + kt) * 4096;

  {   // stage 64x64 of K and V (coalesced)
    const int r0 = t >> 3, c8 = (t & 7) * 8;
#pragma unroll
    for (int i = 0; i < 2; ++i) {
      const int r = r0 + i * 32;
      const bf16_t* src = QKVb + (size_t)(b * S_ + kt * 64 + r) * NQKV + 1024 + kvh * DH_ + c8;
      *(bf16x8*)&Lk[r][c8] = *(const bf16x8*)src;
      *(bf16x8*)&Lv[r][c8] = *(const bf16x8*)(src + 256);
    }
  }
  __syncthreads();
  {   // K: rope + swizzle
    const int key = t & 63, cg = t >> 6;        // d0 = cg*16
    const int srow = kt * 64 + key;
    bf16x8 a = *(const bf16x8*)&Lk[key][cg * 16];
    bf16x8 c = *(const bf16x8*)&Lk[key][cg * 16 + 8];
    const float2* lp = lut + srow * 32 + ((cg & 1) * 16);
    float v[16];
#pragma unroll
    for (int i = 0; i < 8; ++i) { v[i] = (float)a[i]; v[i + 8] = (float)c[i]; }
    bf16x8 o0, o1;
#pragma unroll
    for (int j = 0; j < 8; ++j) {
      const float2 ce = lp[2 * j], co = lp[2 * j + 1];
      const float y0 = v[2*j] * ce.x - v[2*j+1] * ce.y;
      const float y1 = v[2*j+1] * co.x + v[2*j] * co.y;
      if (j < 4) { o0[2*j] = (bf16_t)y0; o0[2*j+1] = (bf16_t)y1; }
      else       { o1[2*(j-4)] = (bf16_t)y0; o1[2*(j-4)+1] = (bf16_t)y1; }
    }
    const int s0 = (2 * cg) ^ (key & 7);
    *(bf16x8*)&Kimg[img + key * 64 + s0 * 8]       = o0;
    *(bf16x8*)&Kimg[img + key * 64 + (s0 ^ 1) * 8] = o1;
  }
  {   // V: transpose + full-bank swizzle
    const int d = t & 63, cg = t >> 6;          // keys cg*16 .. +15
#pragma unroll
    for (int g4 = 0; g4 < 4; ++g4) {
      const int g = cg * 4 + g4;                // key group (4 keys)
      f16x4 o;
#pragma unroll
      for (int j = 0; j < 4; ++j)
        o[j] = (f16_t)(float)Lv[g * 4 + j][d];
      const int slot = g ^ (d & 15);
      *(f16x4*)&Vimg[img + d * 64 + slot * 4] = o;
    }
  }
}

// ---------------------------------------------------------------------------
// attn_v6: block = (32-row q-tile, kvh, b); 4 waves = the 4 heads of the
// kv-group, sharing one K/V tile. All waves have IDENTICAL causal extent
// (block-uniform nkt, no idle waves). LDS double-buffered with prefetch
// issued after the barrier (drain overlaps compute). Static softmax,
// exp2 domain, conflict-free swizzled K/V reads (all proven in R8).
// ---------------------------------------------------------------------------
__global__ __launch_bounds__(256, 2) void attn_v6(
    const bf16_t* __restrict__ QKVb, const float2* __restrict__ lut,
    const bf16_t* __restrict__ Kt2, const f16_t* __restrict__ Vt2,
    const int* __restrict__ amask, bf16_t* __restrict__ Ab)
{
  __shared__ __align__(16) bf16_t Ks[2][64 * 64];   // 16 KB
  __shared__ __align__(16) f16_t  Vs[2][64 * 64];   // 16 KB

  const int tid  = threadIdx.x;
  const int w    = tid >> 6;
  const int lane = tid & 63;
  const int m    = lane & 15;
  const int quad = lane >> 4;
  const int kvh  = blockIdx.y;
  const int b    = blockIdx.z;
  const int h    = kvh * 4 + w;           // each wave owns one head
  const int qt   = 63 - blockIdx.x;       // longest blocks first
  const int q0w  = qt * 32;
  const int nkt  = ((q0w + 31) >> 6) + 1; // block-uniform

  // ---- Q fragments with fused RoPE + scale ----
  bf16x8 aq[2][2];
#pragma unroll
  for (int mt = 0; mt < 2; ++mt) {
    const int spos = q0w + mt * 16 + m;
    const bf16_t* qsrc = QKVb + (size_t)(b * S_ + spos) * NQKV + h * DH_;
    float2 l8[8];
#pragma unroll
    for (int j = 0; j < 8; ++j) l8[j] = lut[spos * 32 + quad * 8 + j];
#pragma unroll
    for (int kc = 0; kc < 2; ++kc) {
      bf16x8 x = *(const bf16x8*)(qsrc + kc * 32 + quad * 8);
      bf16x8 y;
#pragma unroll
      for (int i = 0; i < 4; ++i) {
        const float x0 = (float)x[2*i], x1 = (float)x[2*i+1];
        y[2*i]   = (bf16_t)((x0 * l8[2*i].x   - x1 * l8[2*i].y)   * QSCALE);
        y[2*i+1] = (bf16_t)((x1 * l8[2*i+1].x + x0 * l8[2*i+1].y) * QSCALE);
      }
      aq[mt][kc] = y;
    }
  }

  f32x4 oacc[2][4];
#pragma unroll
  for (int mt = 0; mt < 2; ++mt)
#pragma unroll
    for (int d = 0; d < 4; ++d) oacc[mt][d] = (f32x4){0.f,0.f,0.f,0.f};
  float lpart[2] = {0.f, 0.f};

  const size_t imgbase = ((size_t)(b * NKV_ + kvh) * 32) * 4096;
  const bf16_t* Kg = Kt2 + imgbase;
  const f16_t*  Vg = Vt2 + imgbase;
  const int x0s = quad ^ (m & 7);
  const int x1s = (4 + quad) ^ (m & 7);
  const int* amp = amask + b * S_;

  // prologue: stage tile 0 into buf 0
  gl_lds16(Kg + (2*w)   * 512 + lane * 8, &Ks[0][(2*w)   * 512]);
  gl_lds16(Kg + (2*w+1) * 512 + lane * 8, &Ks[0][(2*w+1) * 512]);
  gl_lds16(Vg + (2*w)   * 512 + lane * 8, &Vs[0][(2*w)   * 512]);
  gl_lds16(Vg + (2*w+1) * 512 + lane * 8, &Vs[0][(2*w+1) * 512]);
  int mcur = amp[lane];

  int p = 0;
  for (int kt = 0; kt < nkt; ++kt) {
    const int kbase = kt * 64;
    __syncthreads();                      // drains buf[p]'s DMA (issued last iter)
    const bool more = (kt + 1 < nkt);
    if (more) {                           // prefetch next tile into buf[p^1]
      const size_t off = (size_t)(kt + 1) * 4096;
      gl_lds16(Kg + off + (2*w)   * 512 + lane * 8, &Ks[p^1][(2*w)   * 512]);
      gl_lds16(Kg + off + (2*w+1) * 512 + lane * 8, &Ks[p^1][(2*w+1) * 512]);
      gl_lds16(Vg + off + (2*w)   * 512 + lane * 8, &Vs[p^1][(2*w)   * 512]);
      gl_lds16(Vg + off + (2*w+1) * 512 + lane * 8, &Vs[p^1][(2*w+1) * 512]);
    }
    int mnext = more ? amp[(kt + 1) * 64 + lane] : 0;
    const uint64_t mb = __ballot(mcur != 0);

    // ---- S^T = K . Q^T ----
    f32x4 sc[2][4];
#pragma unroll
    for (int mt = 0; mt < 2; ++mt)
#pragma unroll
      for (int cb = 0; cb < 4; ++cb) sc[mt][cb] = (f32x4){0.f,0.f,0.f,0.f};
#pragma unroll
    for (int cb = 0; cb < 4; ++cb) {
      const bf16x8 bk0 = *(const bf16x8*)&Ks[p][(cb*16 + m) * 64 + x0s * 8];
      const bf16x8 bk1 = *(const bf16x8*)&Ks[p][(cb*16 + m) * 64 + x1s * 8];
#pragma unroll
      for (int mt = 0; mt < 2; ++mt) {
        sc[mt][cb] = __builtin_amdgcn_mfma_f32_16x16x32_bf16(bk0, aq[mt][0], sc[mt][cb], 0, 0, 0);
        sc[mt][cb] = __builtin_amdgcn_mfma_f32_16x16x32_bf16(bk1, aq[mt][1], sc[mt][cb], 0, 0, 0);
      }
    }

    // ---- static softmax: p = exp2(s), masked -> 0 ----
    f16x4 bp[2][4];
#pragma unroll
    for (int mt = 0; mt < 2; ++mt) {
      const bool needm = (kbase + 63 > q0w + mt*16) || (mb != ~0ull);
      if (needm) {
        const int qv = q0w + mt*16 + m;
#pragma unroll
        for (int cb = 0; cb < 4; ++cb)
#pragma unroll
          for (int r = 0; r < 4; ++r) {
            const int idx = cb*16 + quad*4 + r;
            const bool ok = (kbase + idx <= qv) && ((mb >> idx) & 1);
            sc[mt][cb][r] = ok ? sc[mt][cb][r] : -1e38f;
          }
      }
      float sum = 0.f;
#pragma unroll
      for (int cb = 0; cb < 4; ++cb) {
        f16x4 pp;
#pragma unroll
        for (int r = 0; r < 4; ++r) {
          const float pv = exp2f(sc[mt][cb][r]);
          sum += pv;
          pp[r] = (f16_t)pv;
        }
        bp[mt][cb] = pp;
      }
      lpart[mt] += sum;
    }

    // ---- O^T += V^T . P^T  (conflict-free swizzle, V shared across mt) ----
#pragma unroll
    for (int cb = 0; cb < 4; ++cb) {
      f16x4 av[4];
#pragma unroll
      for (int dblk = 0; dblk < 4; ++dblk) {
        const int slot = (cb * 4 + quad) ^ m;
        av[dblk] = *(const f16x4*)&Vs[p][(dblk*16 + m) * 64 + slot * 4];
      }
#pragma unroll
      for (int mt = 0; mt < 2; ++mt)
#pragma unroll
        for (int dblk = 0; dblk < 4; ++dblk)
          oacc[mt][dblk] = __builtin_amdgcn_mfma_f32_16x16x16f16(av[dblk], bp[mt][cb], oacc[mt][dblk], 0, 0, 0);
    }
    mcur = mnext;
    p ^= 1;
  }

  // ---- epilogue: reduce l across quads, store O ----
#pragma unroll
  for (int mt = 0; mt < 2; ++mt) {
    float l = lpart[mt];
    l += __shfl_xor(l, 16);
    l += __shfl_xor(l, 32);
    const float inv = 1.0f / l;
    const size_t row = (size_t)(b * S_ + q0w + mt*16 + m);
#pragma unroll
    for (int dblk = 0; dblk < 4; ++dblk) {
      bf16x4 o;
      o[0] = (bf16_t)(oacc[mt][dblk][0] * inv);
      o[1] = (bf16_t)(oacc[mt][dblk][1] * inv);
      o[2] = (bf16_t)(oacc[mt][dblk][2] * inv);
      o[3] = (bf16_t)(oacc[mt][dblk][3] * inv);
      *(bf16x4*)&Ab[row * HID + h * DH_ + dblk * 16 + quad * 4] = o;
    }
  }
}

// ---------------------------------------------------------------------------
extern "C" void kernel_launch(void* const* d_in, const int* in_sizes, int n_in,
                              void* d_out, int out_size, void* d_ws, size_t ws_size,
                              hipStream_t stream)
{
  const float* hs    = (const float*)d_in[0];
  const int*   amask = (const int*)  d_in[1];
  const float* Wq    = (const float*)d_in[2];
  const float* bq    = (const float*)d_in[3];
  const float* Wk    = (const float*)d_in[4];
  const float* bk    = (const float*)d_in[5];
  const float* Wv    = (const float*)d_in[6];
  const float* bv    = (const float*)d_in[7];
  const float* Wo    = (const float*)d_in[8];
  const float* bo    = (const float*)d_in[9];
  float* out = (float*)d_out;

  // workspace layout (~31 MB)
  bf16_t* QKVb = (bf16_t*)d_ws;                            // 12.6 MB (live through attn)
  bf16_t* hsb  = QKVb + (size_t)ROWS * NQKV;               // 8 MB (Ab aliases after QKV GEMM)
  bf16_t* Wt   = hsb + (size_t)ROWS * HID;                 // 3 MB
  bf16_t* Wot  = Wt + (size_t)NQKV * HID;                  // 2 MB
  float*  ball = (float*)(Wot + (size_t)HID * HID);        // 6 KB
  bf16_t* Kimg = (bf16_t*)(ball + NQKV);                   // 2 MB
  f16_t*  Vimg = (f16_t*)(Kimg + (size_t)B_*NKV_*32*4096); // 2 MB
  float2* lut  = (float2*)(Vimg + (size_t)B_*NKV_*32*4096);// 0.5 MB
  bf16_t* Ab   = hsb;                                      // alias (hsb dead after QKV GEMM)

  // fused prep: cast + weight transpose + biases + RoPE LUT
  prep_all<<<4870, 256, 0, stream>>>(hs, Wq, Wk, Wv, Wo, bq, bk, bv,
                                     hsb, Wt, Wot, ball, lut);

  // QKV projection (bf16 out, 768 blocks = 3/CU, dbuf)
  gemm64_b16o<<<dim3(NQKV/64, ROWS/128), 256, 0, stream>>>(hsb, Wt, ball, QKVb, NQKV);

  // K/V tile images (swizzled, roped K, transposed V)
  prep_kv<<<256, 256, 0, stream>>>(QKVb, lut, Kimg, Vimg);

  // attention (4 heads per block, dbuf prefetch, 512 blocks)
  attn_v6<<<dim3(64, NKV_, B_), 256, 0, stream>>>(QKVb, lut, Kimg, Vimg, amask, Ab);

  // output projection (512 blocks = 2/CU, dbuf)
  gemm64_f32o<<<dim3(HID/64, ROWS/128), 256, 0, stream>>>(Ab, Wot, bo, out, HID);
}